// Round 8
// baseline (276.309 us; speedup 1.0000x reference)
//
#include <hip/hip_runtime.h>
#include <math.h>

#define SEQ 4096
#define DMODEL 1024
#define NH 16
#define DK 64
#define LDP 72   // padded LDS row (16-bit elems): conflict-free b64/b128 frag reads

typedef __bf16    bf16x8 __attribute__((ext_vector_type(8)));
typedef float     f32x4  __attribute__((ext_vector_type(4)));
typedef _Float16  h16x4  __attribute__((ext_vector_type(4)));
typedef _Float16  h16x8  __attribute__((ext_vector_type(8)));

// global->LDS DMA, 16 B per lane; LDS dest = uniform base + lane*16 (no pad!)
#define GLOAD_LDS16(g, l) __builtin_amdgcn_global_load_lds(                     \
    (const __attribute__((address_space(1))) unsigned int*)(g),                 \
    (__attribute__((address_space(3))) unsigned int*)(l), 16, 0, 0)

// ---------------------------------------------------------------------------
// Convert x (4M) + Wq/Wk/Wv/Wo (1M each) fp32 -> bf16 into contiguous ws.
// ---------------------------------------------------------------------------
__global__ __launch_bounds__(256)
void cvt_all(const float* __restrict__ x, const float* __restrict__ Wq,
             const float* __restrict__ Wk, const float* __restrict__ Wv,
             const float* __restrict__ Wo, __bf16* __restrict__ dst)
{
    const size_t M1 = 1u << 20;
    const size_t e = ((size_t)blockIdx.x * 256 + threadIdx.x) * 8;
    const float* src; size_t off;
    if      (e < 4*M1) { src = x;  off = e;        }
    else if (e < 5*M1) { src = Wq; off = e - 4*M1; }
    else if (e < 6*M1) { src = Wk; off = e - 5*M1; }
    else if (e < 7*M1) { src = Wv; off = e - 6*M1; }
    else               { src = Wo; off = e - 7*M1; }
    const float4 f0 = *reinterpret_cast<const float4*>(&src[off]);
    const float4 f1 = *reinterpret_cast<const float4*>(&src[off + 4]);
    bf16x8 pk;
    pk[0]=(__bf16)f0.x; pk[1]=(__bf16)f0.y; pk[2]=(__bf16)f0.z; pk[3]=(__bf16)f0.w;
    pk[4]=(__bf16)f1.x; pk[5]=(__bf16)f1.y; pk[6]=(__bf16)f1.z; pk[7]=(__bf16)f1.w;
    *reinterpret_cast<bf16x8*>(&dst[e]) = pk;
}

// ---------------------------------------------------------------------------
// 128x128 GEMM core with global_load_lds staging (XOR chunk swizzle).
// ---------------------------------------------------------------------------
__device__ __forceinline__ void gemm_core128(const __bf16* __restrict__ A,
                                             const __bf16* __restrict__ W,
                                             int m0, int n0, int t,
                                             __bf16* AsF, __bf16* BsF,
                                             f32x4 acc[4][4])
{
    const int w = t >> 6, lane = t & 63, l15 = lane & 15, quad = lane >> 4;
    const int wm = (w & 1) * 64, wn = (w >> 1) * 64;
    const int lr = lane >> 3, lc = lane & 7;
    for (int k0 = 0; k0 < DMODEL; k0 += 64) {
        __syncthreads();
        #pragma unroll
        for (int p = 0; p < 4; ++p) {
            const int n = w*4 + p;
            const int r = n*8 + lr;
            const int cl = lc ^ (r & 7);
            GLOAD_LDS16(&A[(size_t)(m0 + r) * DMODEL + k0 + cl*8], &AsF[n*512]);
            GLOAD_LDS16(&W[(size_t)(n0 + r) * DMODEL + k0 + cl*8], &BsF[n*512]);
        }
        __syncthreads();
        #pragma unroll
        for (int kb = 0; kb < 2; ++kb) {
            const int phys = ((kb*4 + quad) ^ (l15 & 7)) * 8;
            bf16x8 af[4], bfr[4];
            #pragma unroll
            for (int i = 0; i < 4; ++i) {
                af[i]  = *reinterpret_cast<const bf16x8*>(&AsF[(wm + i*16 + l15)*64 + phys]);
                bfr[i] = *reinterpret_cast<const bf16x8*>(&BsF[(wn + i*16 + l15)*64 + phys]);
            }
            #pragma unroll
            for (int ms = 0; ms < 4; ++ms)
                #pragma unroll
                for (int ns = 0; ns < 4; ++ns)
                    acc[ms][ns] = __builtin_amdgcn_mfma_f32_16x16x32_bf16(af[ms], bfr[ns], acc[ms][ns], 0, 0, 0);
        }
    }
}

// ---------------------------------------------------------------------------
// Fused QKV projection -> fp16. [0,1024)=Q scaled 0.125*log2e; [1024,2048)=K;
// [2048,3072)=V transposed Vt[d][s]. Q/K epilogue: per-wave LDS transpose ->
// coalesced 16B stores (was 32 scalar 2B stores/lane).
// ---------------------------------------------------------------------------
__global__ __launch_bounds__(256, 3)
void gemm_qkv(const __bf16* __restrict__ xb, const __bf16* __restrict__ Wcat,
              const float* __restrict__ bq, const float* __restrict__ bk,
              const float* __restrict__ bv,
              _Float16* __restrict__ Qh, _Float16* __restrict__ Kh, _Float16* __restrict__ Vth)
{
    __shared__ __bf16 SM[4*64*LDP];      // 36864 B; staging uses first 32 KB
    __bf16* AsF = SM;
    __bf16* BsF = SM + 8192;
    const int t = threadIdx.x;
    const int n0g = blockIdx.x * 128;
    const int m0  = blockIdx.y * 128;
    const int which = n0g >> 10;
    const int n_in  = n0g & 1023;

    f32x4 acc[4][4] = {};
    gemm_core128(xb, Wcat, m0, n0g, t, AsF, BsF, acc);

    const int w = t >> 6, lane = t & 63, l15 = lane & 15, quad = lane >> 4;
    const int wm = (w & 1) * 64, wn = (w >> 1) * 64;
    const float* bias = (which == 0) ? bq : (which == 1) ? bk : bv;
    float br[4];
    #pragma unroll
    for (int ns = 0; ns < 4; ++ns) br[ns] = bias[n_in + wn + ns*16 + l15];

    if (which == 2) {
        #pragma unroll
        for (int ms = 0; ms < 4; ++ms)
            #pragma unroll
            for (int ns = 0; ns < 4; ++ns) {
                h16x4 pk;
                #pragma unroll
                for (int rg = 0; rg < 4; ++rg) pk[rg] = (_Float16)(acc[ms][ns][rg] + br[ns]);
                *reinterpret_cast<h16x4*>(
                    &Vth[(size_t)(n_in + wn + ns*16 + l15) * SEQ + m0 + wm + ms*16 + quad*4]) = pk;
            }
    } else {
        const float s = (which == 0) ? 0.1803368787f : 1.0f;  // 0.125 * log2(e)
        _Float16* C = (which == 0) ? Qh : Kh;
        __syncthreads();   // all waves done with staging LDS
        _Float16* tile = (_Float16*)SM + w * 64 * LDP;   // per-wave 64x72 region
        #pragma unroll
        for (int ms = 0; ms < 4; ++ms)
            #pragma unroll
            for (int ns = 0; ns < 4; ++ns)
                #pragma unroll
                for (int rg = 0; rg < 4; ++rg)
                    tile[(ms*16 + quad*4 + rg) * LDP + ns*16 + l15] =
                        (_Float16)((acc[ms][ns][rg] + br[ns]) * s);
        asm volatile("s_waitcnt lgkmcnt(0)" ::: "memory");   // same-wave drain
        const int er = lane >> 3, ec = (lane & 7) * 8;
        #pragma unroll
        for (int p = 0; p < 8; ++p) {
            const h16x8 v = *reinterpret_cast<const h16x8*>(&tile[(er + p*8) * LDP + ec]);
            *reinterpret_cast<h16x8*>(
                &C[(size_t)(m0 + wm + er + p*8) * DMODEL + n_in + wn + ec]) = v;
        }
    }
}

// ---------------------------------------------------------------------------
// 128x64 GEMM core with DMA staging, for the output projection.
// ---------------------------------------------------------------------------
__device__ __forceinline__ void gemm_core64(const __bf16* __restrict__ A,
                                            const __bf16* __restrict__ W,
                                            int m0, int n0, int t,
                                            __bf16* AsF, __bf16* BsF,
                                            f32x4 acc[2][4])
{
    const int w = t >> 6, lane = t & 63, l15 = lane & 15, quad = lane >> 4;
    const int lr = lane >> 3, lc = lane & 7;
    for (int k0 = 0; k0 < DMODEL; k0 += 64) {
        __syncthreads();
        #pragma unroll
        for (int p = 0; p < 4; ++p) {
            const int n = w*4 + p;
            const int r = n*8 + lr;
            const int cl = lc ^ (r & 7);
            GLOAD_LDS16(&A[(size_t)(m0 + r) * DMODEL + k0 + cl*8], &AsF[n*512]);
        }
        #pragma unroll
        for (int p = 0; p < 2; ++p) {
            const int n = w*2 + p;
            const int r = n*8 + lr;
            const int cl = lc ^ (r & 7);
            GLOAD_LDS16(&W[(size_t)(n0 + r) * DMODEL + k0 + cl*8], &BsF[n*512]);
        }
        __syncthreads();
        #pragma unroll
        for (int kb = 0; kb < 2; ++kb) {
            const int phys = ((kb*4 + quad) ^ (l15 & 7)) * 8;
            bf16x8 af0 = *reinterpret_cast<const bf16x8*>(&AsF[(w*32 + l15)*64 + phys]);
            bf16x8 af1 = *reinterpret_cast<const bf16x8*>(&AsF[(w*32 + 16 + l15)*64 + phys]);
            #pragma unroll
            for (int ns = 0; ns < 4; ++ns) {
                const bf16x8 bfr = *reinterpret_cast<const bf16x8*>(&BsF[(ns*16 + l15)*64 + phys]);
                acc[0][ns] = __builtin_amdgcn_mfma_f32_16x16x32_bf16(af0, bfr, acc[0][ns], 0, 0, 0);
                acc[1][ns] = __builtin_amdgcn_mfma_f32_16x16x32_bf16(af1, bfr, acc[1][ns], 0, 0, 0);
            }
        }
    }
}

__global__ __launch_bounds__(256, 4)
void gemm_out(const __bf16* __restrict__ Ob, const __bf16* __restrict__ Wob,
              const float* __restrict__ bo, float* __restrict__ out)
{
    __shared__ __bf16 AsF[128*64];
    __shared__ __bf16 BsF[64*64];
    const int t = threadIdx.x;
    const int n0 = blockIdx.x * 64;
    const int m0 = blockIdx.y * 128;

    f32x4 acc[2][4] = {};
    gemm_core64(Ob, Wob, m0, n0, t, AsF, BsF, acc);

    const int lane = t & 63, l15 = lane & 15, quad = lane >> 4, w = t >> 6;
    float br[4];
    #pragma unroll
    for (int ns = 0; ns < 4; ++ns) br[ns] = bo[n0 + ns*16 + l15];
    #pragma unroll
    for (int ms = 0; ms < 2; ++ms)
        #pragma unroll
        for (int ns = 0; ns < 4; ++ns)
            #pragma unroll
            for (int rg = 0; rg < 4; ++rg)
                out[(size_t)(m0 + w*32 + ms*16 + quad*4 + rg) * DMODEL + n0 + ns*16 + l15] =
                    acc[ms][ns][rg] + br[ns];
}

// ---------------------------------------------------------------------------
// Causal flash attention, SPLIT-KV with 16-tile chunks + fp32 atomic combine.
// Block = 256 thr (4 waves) = 64-row q-tile x one 16-tile KV chunk.
// Unit map (u in [0,160)): g=0: qt=63-u (u<64); g=1: qt=127-u (u<112);
// g=2: qt=175-u (u<144); g=3: qt=207-u. Chunk g covers tiles [16g, min(16g+15,qt)].
// qt<16 (single chunk): normalize in-kernel, write bf16 Ob directly.
// else: atomicAdd unnormalized acc into accb (d_out scratch) + row-sums into lbuf;
// norm_o kernel finishes rows >= 1024.
// ---------------------------------------------------------------------------
__global__ __launch_bounds__(256, 8)
void attn_mfma(const _Float16* __restrict__ Q, const _Float16* __restrict__ K,
               const _Float16* __restrict__ Vt, __bf16* __restrict__ O,
               float* __restrict__ accb, float* __restrict__ lbuf)
{
    __shared__ _Float16 KsF[64*64];      // [key][d] unpadded, chunk-swizzled (DMA)
    __shared__ _Float16 Vts[64][LDP];    // [d][key] padded, regular staging

    const int t = threadIdx.x;
    const int w = t >> 6;
    const int lane = t & 63, l15 = lane & 15, quad = lane >> 4;
    const int lr = lane >> 3, lc = lane & 7;
    const int h = blockIdx.y;
    const int u = blockIdx.x;
    int qt, g;
    if      (u < 64)  { g = 0; qt = 63 - u;  }
    else if (u < 112) { g = 1; qt = 127 - u; }
    else if (u < 144) { g = 2; qt = 175 - u; }
    else              { g = 3; qt = 207 - u; }
    const int tstart = g * 16;
    const int tend   = (qt < tstart + 15) ? qt : (tstart + 15);
    const int wr0 = qt*64 + w*16;

    // Q B-frags (x32: lane n=q=l15 holds d=quad*8+j), loaded once.
    h16x8 bq8[2];
    #pragma unroll
    for (int kb = 0; kb < 2; ++kb)
        bq8[kb] = *reinterpret_cast<const h16x8*>(
            &Q[(size_t)(wr0 + l15) * DMODEL + h*DK + kb*32 + quad*8]);

    f32x4 acc[4] = {};      // PV C-layout: col=d=l15, row=q=quad*4+rg
    float lsum = 0.f;       // per-lane partial denom for q-row l15

    for (int tk = tstart; tk <= tend; ++tk) {
        const int j0 = tk * 64;
        __syncthreads();    // prev iteration's readers done
        #pragma unroll
        for (int p = 0; p < 2; ++p) {
            const int idx = t + p * 256;
            const int r = idx >> 3, c = (idx & 7) * 8;
            *reinterpret_cast<h16x8*>(&Vts[r][c]) =
                *reinterpret_cast<const h16x8*>(&Vt[(size_t)(h*DK + r) * SEQ + j0 + c]);
        }
        #pragma unroll
        for (int p = 0; p < 2; ++p) {
            const int n = w*2 + p;
            const int r = n*8 + lr;
            const int cl = lc ^ (r & 7);
            GLOAD_LDS16(&K[(size_t)(j0 + r) * DMODEL + h*DK + cl*8], &KsF[n*512]);
        }
        __syncthreads();    // drains vmcnt (DMA) + lgkm for all waves

        // ---- S^T = K . Q^T (x32), 4 key-subtiles; P packed in-register ----
        h16x4 ap[4];
        const bool msk = (j0 + 63 > wr0);
        const int rel = wr0 - j0 + l15;
        #pragma unroll
        for (int st = 0; st < 4; ++st) {
            f32x4 cc = {0.f, 0.f, 0.f, 0.f};
            #pragma unroll
            for (int kb = 0; kb < 2; ++kb) {
                const h16x8 ak = *reinterpret_cast<const h16x8*>(
                    &KsF[(st*16 + l15)*64 + (((kb*4 + quad) ^ (l15 & 7)))*8]);
                cc = __builtin_amdgcn_mfma_f32_16x16x32_f16(ak, bq8[kb], cc, 0, 0, 0);
            }
            #pragma unroll
            for (int rg = 0; rg < 4; ++rg) {
                float pv = exp2f(cc[rg]);
                if (msk && (st*16 + quad*4 + rg > rel)) pv = 0.f;
                lsum += pv;
                ap[st][rg] = (_Float16)pv;
            }
        }

        // ---- O^ += P . V (x16) ----
        #pragma unroll
        for (int ds_ = 0; ds_ < 4; ++ds_) {
            #pragma unroll
            for (int st = 0; st < 4; ++st) {
                const h16x4 bv = *reinterpret_cast<const h16x4*>(
                    &Vts[ds_*16 + l15][st*16 + quad*4]);
                acc[ds_] = __builtin_amdgcn_mfma_f32_16x16x16f16(ap[st], bv, acc[ds_], 0, 0, 0);
            }
        }
    }

    // ---- denom reduce: lane l15 -> full sum for q-row l15 ----
    float ls = lsum;
    ls += __shfl_xor(ls, 16);
    ls += __shfl_xor(ls, 32);

    if (qt < 16) {
        #pragma unroll
        for (int rg = 0; rg < 4; ++rg) {
            const float dn = __shfl(ls, quad*4 + rg);
            const float inv = 1.0f / dn;
            const size_t row = (size_t)(wr0 + quad*4 + rg) * DMODEL + h * DK;
            #pragma unroll
            for (int ds_ = 0; ds_ < 4; ++ds_)
                O[row + ds_*16 + l15] = (__bf16)(acc[ds_][rg] * inv);
        }
    } else {
        #pragma unroll
        for (int rg = 0; rg < 4; ++rg) {
            const size_t row = (size_t)(wr0 + quad*4 + rg) * DMODEL + h * DK;
            #pragma unroll
            for (int ds_ = 0; ds_ < 4; ++ds_)
                atomicAdd(&accb[row + ds_*16 + l15], acc[ds_][rg]);
        }
        if (quad == 0) atomicAdd(&lbuf[h * SEQ + wr0 + l15], ls);
    }
}

// ---------------------------------------------------------------------------
// Normalize atomic-combined rows (>= 1024): Ob = accb / lbuf.
// ---------------------------------------------------------------------------
__global__ __launch_bounds__(256)
void norm_o(const float* __restrict__ accb, const float* __restrict__ lbuf,
            __bf16* __restrict__ O)
{
    const size_t e = (1u << 20) + ((size_t)blockIdx.x * 256 + threadIdx.x) * 8;
    const int row = (int)(e >> 10);
    const int hh  = ((int)e & 1023) >> 6;
    const float inv = 1.0f / lbuf[hh * SEQ + row];
    const float4 p0 = *reinterpret_cast<const float4*>(&accb[e]);
    const float4 p1 = *reinterpret_cast<const float4*>(&accb[e + 4]);
    bf16x8 pk;
    pk[0]=(__bf16)(p0.x*inv); pk[1]=(__bf16)(p0.y*inv);
    pk[2]=(__bf16)(p0.z*inv); pk[3]=(__bf16)(p0.w*inv);
    pk[4]=(__bf16)(p1.x*inv); pk[5]=(__bf16)(p1.y*inv);
    pk[6]=(__bf16)(p1.z*inv); pk[7]=(__bf16)(p1.w*inv);
    *reinterpret_cast<bf16x8*>(&O[e]) = pk;
}

// ---------------------------------------------------------------------------
extern "C" void kernel_launch(void* const* d_in, const int* in_sizes, int n_in,
                              void* d_out, int out_size, void* d_ws, size_t ws_size,
                              hipStream_t stream) {
    const float* x  = (const float*)d_in[0];
    const float* Wq = (const float*)d_in[1];
    const float* bq = (const float*)d_in[2];
    const float* Wk = (const float*)d_in[3];
    const float* bk = (const float*)d_in[4];
    const float* Wv = (const float*)d_in[5];
    const float* bv = (const float*)d_in[6];
    const float* Wo = (const float*)d_in[7];
    const float* bo = (const float*)d_in[8];
    float* out = (float*)d_out;

    const size_t M1 = 1u << 20;
    __bf16* base = (__bf16*)d_ws;
    __bf16*    xb   = base;                          // 4M bf16
    __bf16*    Wcat = base + 4*M1;                   // Wq|Wk|Wv (3M bf16)
    __bf16*    Wob  = base + 7*M1;                   // 1M bf16
    _Float16*  Qh   = (_Float16*)(base + 8*M1);      // 4M fp16 each
    _Float16*  Kh   = (_Float16*)(base + 12*M1);
    _Float16*  Vth  = (_Float16*)(base + 16*M1);
    __bf16*    Ob   = base + 20*M1;                  // 4M bf16
    float*     lbuf = (float*)(base + 24*M1);        // 16*4096 fp32 = 256 KB
    float*     accb = out;                           // fp32 O-accumulator: exact 16 MB

    hipMemsetAsync(accb, 0, (size_t)out_size * sizeof(float), stream);
    hipMemsetAsync(lbuf, 0, (size_t)NH * SEQ * sizeof(float), stream);

    cvt_all<<<4096, 256, 0, stream>>>(x, Wq, Wk, Wv, Wo, base);
    gemm_qkv<<<dim3(24, 32), 256, 0, stream>>>(xb, Wcat, bq, bk, bv, Qh, Kh, Vth);
    attn_mfma<<<dim3(160, NH), 256, 0, stream>>>(Qh, Kh, Vth, Ob, accb, lbuf);
    norm_o<<<1536, 256, 0, stream>>>(accb, lbuf, Ob);
    gemm_out<<<dim3(16, 32), 256, 0, stream>>>(Ob, Wob, bo, out);
}

// Round 9
// 221.278 us; speedup vs baseline: 1.2487x; 1.2487x over previous
//
#include <hip/hip_runtime.h>
#include <math.h>

#define SEQ 4096
#define DMODEL 1024
#define NH 16
#define DK 64
#define LDP 72   // padded LDS row (16-bit elems): conflict-free b64/b128 frag reads

typedef __bf16    bf16x8 __attribute__((ext_vector_type(8)));
typedef float     f32x4  __attribute__((ext_vector_type(4)));
typedef _Float16  h16x4  __attribute__((ext_vector_type(4)));
typedef _Float16  h16x8  __attribute__((ext_vector_type(8)));

// global->LDS DMA, 16 B per lane; LDS dest = uniform base + lane*16 (no pad!)
#define GLOAD_LDS16(g, l) __builtin_amdgcn_global_load_lds(                     \
    (const __attribute__((address_space(1))) unsigned int*)(g),                 \
    (__attribute__((address_space(3))) unsigned int*)(l), 16, 0, 0)

// ---------------------------------------------------------------------------
// Convert x (4M) + Wq/Wk/Wv/Wo (1M each) fp32 -> bf16 into contiguous ws.
// ---------------------------------------------------------------------------
__global__ __launch_bounds__(256)
void cvt_all(const float* __restrict__ x, const float* __restrict__ Wq,
             const float* __restrict__ Wk, const float* __restrict__ Wv,
             const float* __restrict__ Wo, __bf16* __restrict__ dst)
{
    const size_t M1 = 1u << 20;
    const size_t e = ((size_t)blockIdx.x * 256 + threadIdx.x) * 8;
    const float* src; size_t off;
    if      (e < 4*M1) { src = x;  off = e;        }
    else if (e < 5*M1) { src = Wq; off = e - 4*M1; }
    else if (e < 6*M1) { src = Wk; off = e - 5*M1; }
    else if (e < 7*M1) { src = Wv; off = e - 6*M1; }
    else               { src = Wo; off = e - 7*M1; }
    const float4 f0 = *reinterpret_cast<const float4*>(&src[off]);
    const float4 f1 = *reinterpret_cast<const float4*>(&src[off + 4]);
    bf16x8 pk;
    pk[0]=(__bf16)f0.x; pk[1]=(__bf16)f0.y; pk[2]=(__bf16)f0.z; pk[3]=(__bf16)f0.w;
    pk[4]=(__bf16)f1.x; pk[5]=(__bf16)f1.y; pk[6]=(__bf16)f1.z; pk[7]=(__bf16)f1.w;
    *reinterpret_cast<bf16x8*>(&dst[e]) = pk;
}

// ---------------------------------------------------------------------------
// 128x128 GEMM core with global_load_lds staging (XOR chunk swizzle).
// ---------------------------------------------------------------------------
__device__ __forceinline__ void gemm_core128(const __bf16* __restrict__ A,
                                             const __bf16* __restrict__ W,
                                             int m0, int n0, int t,
                                             __bf16* AsF, __bf16* BsF,
                                             f32x4 acc[4][4])
{
    const int w = t >> 6, lane = t & 63, l15 = lane & 15, quad = lane >> 4;
    const int wm = (w & 1) * 64, wn = (w >> 1) * 64;
    const int lr = lane >> 3, lc = lane & 7;
    for (int k0 = 0; k0 < DMODEL; k0 += 64) {
        __syncthreads();
        #pragma unroll
        for (int p = 0; p < 4; ++p) {
            const int n = w*4 + p;
            const int r = n*8 + lr;
            const int cl = lc ^ (r & 7);
            GLOAD_LDS16(&A[(size_t)(m0 + r) * DMODEL + k0 + cl*8], &AsF[n*512]);
            GLOAD_LDS16(&W[(size_t)(n0 + r) * DMODEL + k0 + cl*8], &BsF[n*512]);
        }
        __syncthreads();
        #pragma unroll
        for (int kb = 0; kb < 2; ++kb) {
            const int phys = ((kb*4 + quad) ^ (l15 & 7)) * 8;
            bf16x8 af[4], bfr[4];
            #pragma unroll
            for (int i = 0; i < 4; ++i) {
                af[i]  = *reinterpret_cast<const bf16x8*>(&AsF[(wm + i*16 + l15)*64 + phys]);
                bfr[i] = *reinterpret_cast<const bf16x8*>(&BsF[(wn + i*16 + l15)*64 + phys]);
            }
            #pragma unroll
            for (int ms = 0; ms < 4; ++ms)
                #pragma unroll
                for (int ns = 0; ns < 4; ++ns)
                    acc[ms][ns] = __builtin_amdgcn_mfma_f32_16x16x32_bf16(af[ms], bfr[ns], acc[ms][ns], 0, 0, 0);
        }
    }
}

// ---------------------------------------------------------------------------
// Fused QKV projection -> fp16. [0,1024)=Q scaled 0.125*log2e; [1024,2048)=K;
// [2048,3072)=V transposed Vt[d][s]. Q/K epilogue via per-wave LDS transpose.
// ---------------------------------------------------------------------------
__global__ __launch_bounds__(256, 3)
void gemm_qkv(const __bf16* __restrict__ xb, const __bf16* __restrict__ Wcat,
              const float* __restrict__ bq, const float* __restrict__ bk,
              const float* __restrict__ bv,
              _Float16* __restrict__ Qh, _Float16* __restrict__ Kh, _Float16* __restrict__ Vth)
{
    __shared__ __bf16 SM[4*64*LDP];      // staging uses first 32 KB
    __bf16* AsF = SM;
    __bf16* BsF = SM + 8192;
    const int t = threadIdx.x;
    const int n0g = blockIdx.x * 128;
    const int m0  = blockIdx.y * 128;
    const int which = n0g >> 10;
    const int n_in  = n0g & 1023;

    f32x4 acc[4][4] = {};
    gemm_core128(xb, Wcat, m0, n0g, t, AsF, BsF, acc);

    const int w = t >> 6, lane = t & 63, l15 = lane & 15, quad = lane >> 4;
    const int wm = (w & 1) * 64, wn = (w >> 1) * 64;
    const float* bias = (which == 0) ? bq : (which == 1) ? bk : bv;
    float br[4];
    #pragma unroll
    for (int ns = 0; ns < 4; ++ns) br[ns] = bias[n_in + wn + ns*16 + l15];

    if (which == 2) {
        #pragma unroll
        for (int ms = 0; ms < 4; ++ms)
            #pragma unroll
            for (int ns = 0; ns < 4; ++ns) {
                h16x4 pk;
                #pragma unroll
                for (int rg = 0; rg < 4; ++rg) pk[rg] = (_Float16)(acc[ms][ns][rg] + br[ns]);
                *reinterpret_cast<h16x4*>(
                    &Vth[(size_t)(n_in + wn + ns*16 + l15) * SEQ + m0 + wm + ms*16 + quad*4]) = pk;
            }
    } else {
        const float s = (which == 0) ? 0.1803368787f : 1.0f;  // 0.125 * log2(e)
        _Float16* C = (which == 0) ? Qh : Kh;
        __syncthreads();   // all waves done with staging LDS
        _Float16* tile = (_Float16*)SM + w * 64 * LDP;   // per-wave 64x72 region
        #pragma unroll
        for (int ms = 0; ms < 4; ++ms)
            #pragma unroll
            for (int ns = 0; ns < 4; ++ns)
                #pragma unroll
                for (int rg = 0; rg < 4; ++rg)
                    tile[(ms*16 + quad*4 + rg) * LDP + ns*16 + l15] =
                        (_Float16)((acc[ms][ns][rg] + br[ns]) * s);
        asm volatile("s_waitcnt lgkmcnt(0)" ::: "memory");   // same-wave drain
        const int er = lane >> 3, ec = (lane & 7) * 8;
        #pragma unroll
        for (int p = 0; p < 8; ++p) {
            const h16x8 v = *reinterpret_cast<const h16x8*>(&tile[(er + p*8) * LDP + ec]);
            *reinterpret_cast<h16x8*>(
                &C[(size_t)(m0 + wm + er + p*8) * DMODEL + n_in + wn + ec]) = v;
        }
    }
}

// ---------------------------------------------------------------------------
// 128x64 GEMM core with DMA staging, for the output projection.
// ---------------------------------------------------------------------------
__device__ __forceinline__ void gemm_core64(const __bf16* __restrict__ A,
                                            const __bf16* __restrict__ W,
                                            int m0, int n0, int t,
                                            __bf16* AsF, __bf16* BsF,
                                            f32x4 acc[2][4])
{
    const int w = t >> 6, lane = t & 63, l15 = lane & 15, quad = lane >> 4;
    const int lr = lane >> 3, lc = lane & 7;
    for (int k0 = 0; k0 < DMODEL; k0 += 64) {
        __syncthreads();
        #pragma unroll
        for (int p = 0; p < 4; ++p) {
            const int n = w*4 + p;
            const int r = n*8 + lr;
            const int cl = lc ^ (r & 7);
            GLOAD_LDS16(&A[(size_t)(m0 + r) * DMODEL + k0 + cl*8], &AsF[n*512]);
        }
        #pragma unroll
        for (int p = 0; p < 2; ++p) {
            const int n = w*2 + p;
            const int r = n*8 + lr;
            const int cl = lc ^ (r & 7);
            GLOAD_LDS16(&W[(size_t)(n0 + r) * DMODEL + k0 + cl*8], &BsF[n*512]);
        }
        __syncthreads();
        #pragma unroll
        for (int kb = 0; kb < 2; ++kb) {
            const int phys = ((kb*4 + quad) ^ (l15 & 7)) * 8;
            bf16x8 af0 = *reinterpret_cast<const bf16x8*>(&AsF[(w*32 + l15)*64 + phys]);
            bf16x8 af1 = *reinterpret_cast<const bf16x8*>(&AsF[(w*32 + 16 + l15)*64 + phys]);
            #pragma unroll
            for (int ns = 0; ns < 4; ++ns) {
                const bf16x8 bfr = *reinterpret_cast<const bf16x8*>(&BsF[(ns*16 + l15)*64 + phys]);
                acc[0][ns] = __builtin_amdgcn_mfma_f32_16x16x32_bf16(af0, bfr, acc[0][ns], 0, 0, 0);
                acc[1][ns] = __builtin_amdgcn_mfma_f32_16x16x32_bf16(af1, bfr, acc[1][ns], 0, 0, 0);
            }
        }
    }
}

__global__ __launch_bounds__(256, 4)
void gemm_out(const __bf16* __restrict__ Ob, const __bf16* __restrict__ Wob,
              const float* __restrict__ bo, float* __restrict__ out)
{
    __shared__ __bf16 AsF[128*64];
    __shared__ __bf16 BsF[64*64];
    const int t = threadIdx.x;
    const int n0 = blockIdx.x * 64;
    const int m0 = blockIdx.y * 128;

    f32x4 acc[2][4] = {};
    gemm_core64(Ob, Wob, m0, n0, t, AsF, BsF, acc);

    const int lane = t & 63, l15 = lane & 15, quad = lane >> 4, w = t >> 6;
    float br[4];
    #pragma unroll
    for (int ns = 0; ns < 4; ++ns) br[ns] = bo[n0 + ns*16 + l15];
    #pragma unroll
    for (int ms = 0; ms < 2; ++ms)
        #pragma unroll
        for (int ns = 0; ns < 4; ++ns)
            #pragma unroll
            for (int rg = 0; rg < 4; ++rg)
                out[(size_t)(m0 + w*32 + ms*16 + quad*4 + rg) * DMODEL + n0 + ns*16 + l15] =
                    acc[ms][ns][rg] + br[ns];
}

// ---------------------------------------------------------------------------
// Causal flash attention: 128-row q-tiles, 2 slices/wave, split-KV (32-tile
// chunks), register-P, sum-only base-2 softmax. Block = 256 thr (4 waves);
// wave w owns rows qt*128+w*16 (slice0) and qt*128+64+w*16 (slice1). K A-frags
// and V B-frags are shared across slices (half the LDS reads per MFMA).
// Unit map (u in [0,48)), built so each CU's 3 units sum to 66 iterations:
//   u<16 : qt=16+u, g=0  (32 tiles)
//   u<32 : qt=u,    g=1  (qt in [16,32), 2qt-30 tiles, ascending)
//   u<48 : qt=47-u, g=0  single-chunk (2qt+2 tiles, descending)
// qt<16: normalize in-kernel -> bf16 Ob. qt>=16: fp32 partials -> part
// (d_out scratch, 512 units x 32 KB = exactly 16 MB) + row sums -> lpart.
// ---------------------------------------------------------------------------
__global__ __launch_bounds__(256, 3)
void attn_mfma(const _Float16* __restrict__ Q, const _Float16* __restrict__ K,
               const _Float16* __restrict__ Vt, __bf16* __restrict__ O,
               float* __restrict__ part, float* __restrict__ lpart)
{
    __shared__ _Float16 KsF[64*64];      // [key][d] unpadded, chunk-swizzled (DMA)
    __shared__ _Float16 Vts[64][LDP];    // [d][key] padded, regular staging

    const int t = threadIdx.x;
    const int w = t >> 6;
    const int lane = t & 63, l15 = lane & 15, quad = lane >> 4;
    const int lr = lane >> 3, lc = lane & 7;
    const int h = blockIdx.y;
    const int u = blockIdx.x;
    int qt, g;
    if      (u < 16) { qt = 16 + u; g = 0; }
    else if (u < 32) { qt = u;      g = 1; }
    else             { qt = 47 - u; g = 0; }
    const int tstart = g * 32;
    const int tlast  = 2*qt + 1;
    const int tend   = (tlast < tstart + 31) ? tlast : (tstart + 31);
    const int s0 = qt*128 + w*16;        // slice0 row base
    const int s1 = s0 + 64;              // slice1 row base

    // Q B-frags (x32: lane n=q=l15 holds d=quad*8+j), both slices, loaded once.
    h16x8 bq8[2][2];
    #pragma unroll
    for (int kb = 0; kb < 2; ++kb) {
        bq8[0][kb] = *reinterpret_cast<const h16x8*>(
            &Q[(size_t)(s0 + l15) * DMODEL + h*DK + kb*32 + quad*8]);
        bq8[1][kb] = *reinterpret_cast<const h16x8*>(
            &Q[(size_t)(s1 + l15) * DMODEL + h*DK + kb*32 + quad*8]);
    }

    f32x4 acc[2][4] = {};        // [slice][dsub]; C-layout: col=d=l15, row=q=quad*4+rg
    float lsum[2] = {0.f, 0.f};  // per-lane denom partial for q-row l15 of each slice

    for (int tk = tstart; tk <= tend; ++tk) {
        const int j0 = tk * 64;
        __syncthreads();    // prev iteration's readers done
        #pragma unroll
        for (int p = 0; p < 2; ++p) {
            const int idx = t + p * 256;
            const int r = idx >> 3, c = (idx & 7) * 8;
            *reinterpret_cast<h16x8*>(&Vts[r][c]) =
                *reinterpret_cast<const h16x8*>(&Vt[(size_t)(h*DK + r) * SEQ + j0 + c]);
        }
        #pragma unroll
        for (int p = 0; p < 2; ++p) {
            const int n = w*2 + p;
            const int r = n*8 + lr;
            const int cl = lc ^ (r & 7);
            GLOAD_LDS16(&K[(size_t)(j0 + r) * DMODEL + h*DK + cl*8], &KsF[n*512]);
        }
        __syncthreads();    // drains vmcnt (DMA) + lgkm for all waves

        const bool act0 = (j0 <= s0 + 15);   // slice0 still in causal range (uniform)
        const bool msk0 = (j0 + 63 > s0);
        const bool msk1 = (j0 + 63 > s1);
        const int rel0 = s0 - j0 + l15;
        const int rel1 = s1 - j0 + l15;

        // ---- S^T = K . Q^T (x32); K A-frags shared by both slices ----
        h16x4 ap[2][4];
        #pragma unroll
        for (int st = 0; st < 4; ++st) {
            const h16x8 ak0 = *reinterpret_cast<const h16x8*>(
                &KsF[(st*16 + l15)*64 + ((quad ^ (l15 & 7)))*8]);
            const h16x8 ak1 = *reinterpret_cast<const h16x8*>(
                &KsF[(st*16 + l15)*64 + (((4 + quad) ^ (l15 & 7)))*8]);
            // slice 1 (always active)
            {
                f32x4 cc = {0.f, 0.f, 0.f, 0.f};
                cc = __builtin_amdgcn_mfma_f32_16x16x32_f16(ak0, bq8[1][0], cc, 0, 0, 0);
                cc = __builtin_amdgcn_mfma_f32_16x16x32_f16(ak1, bq8[1][1], cc, 0, 0, 0);
                #pragma unroll
                for (int rg = 0; rg < 4; ++rg) {
                    float pv = exp2f(cc[rg]);
                    if (msk1 && (st*16 + quad*4 + rg > rel1)) pv = 0.f;
                    lsum[1] += pv;
                    ap[1][st][rg] = (_Float16)pv;
                }
            }
            // slice 0
            if (act0) {
                f32x4 cc = {0.f, 0.f, 0.f, 0.f};
                cc = __builtin_amdgcn_mfma_f32_16x16x32_f16(ak0, bq8[0][0], cc, 0, 0, 0);
                cc = __builtin_amdgcn_mfma_f32_16x16x32_f16(ak1, bq8[0][1], cc, 0, 0, 0);
                #pragma unroll
                for (int rg = 0; rg < 4; ++rg) {
                    float pv = exp2f(cc[rg]);
                    if (msk0 && (st*16 + quad*4 + rg > rel0)) pv = 0.f;
                    lsum[0] += pv;
                    ap[0][st][rg] = (_Float16)pv;
                }
            }
        }

        // ---- O^ += P . V (x16); V B-frags shared by both slices ----
        #pragma unroll
        for (int ds_ = 0; ds_ < 4; ++ds_) {
            #pragma unroll
            for (int st = 0; st < 4; ++st) {
                const h16x4 bv = *reinterpret_cast<const h16x4*>(
                    &Vts[ds_*16 + l15][st*16 + quad*4]);
                acc[1][ds_] = __builtin_amdgcn_mfma_f32_16x16x16f16(ap[1][st], bv, acc[1][ds_], 0, 0, 0);
                if (act0)
                    acc[0][ds_] = __builtin_amdgcn_mfma_f32_16x16x16f16(ap[0][st], bv, acc[0][ds_], 0, 0, 0);
            }
        }
    }

    // ---- denom reduce per slice: lane l15 -> full sum for its q-row ----
    float ls[2];
    #pragma unroll
    for (int s = 0; s < 2; ++s) {
        float v = lsum[s];
        v += __shfl_xor(v, 16);
        v += __shfl_xor(v, 32);
        ls[s] = v;
    }

    if (qt < 16) {
        #pragma unroll
        for (int s = 0; s < 2; ++s) {
            const int base = s ? s1 : s0;
            #pragma unroll
            for (int rg = 0; rg < 4; ++rg) {
                const float dn = __shfl(ls[s], quad*4 + rg);
                const float inv = 1.0f / dn;
                const size_t row = (size_t)(base + quad*4 + rg) * DMODEL + h * DK;
                #pragma unroll
                for (int ds_ = 0; ds_ < 4; ++ds_)
                    O[row + ds_*16 + l15] = (__bf16)(acc[s][ds_][rg] * inv);
            }
        }
    } else {
        const int unit = (h*16 + (qt - 16))*2 + g;
        const size_t pb = (size_t)unit * 8192;     // 128 rows x 64 d fp32
        #pragma unroll
        for (int s = 0; s < 2; ++s) {
            #pragma unroll
            for (int rg = 0; rg < 4; ++rg) {
                const int lrow = s*64 + w*16 + quad*4 + rg;
                #pragma unroll
                for (int ds_ = 0; ds_ < 4; ++ds_)
                    part[pb + lrow*64 + ds_*16 + l15] = acc[s][ds_][rg];
            }
            if (quad == 0) lpart[unit*128 + s*64 + w*16 + l15] = ls[s];
        }
    }
}

// ---------------------------------------------------------------------------
// Combine the two KV-chunk partials for qt in [16,32): O = (p0+p1)/(l0+l1).
// ---------------------------------------------------------------------------
__global__ __launch_bounds__(256)
void attn_combine(const float* __restrict__ part, const float* __restrict__ lpart,
                  __bf16* __restrict__ O)
{
    const int t = threadIdx.x;
    const int qtp = blockIdx.x;          // 0..15 -> qt = 16+qtp
    const int h = blockIdx.y;
    const int u0 = (h*16 + qtp)*2;
    const size_t b0 = (size_t)u0 * 8192;
    const size_t b1 = b0 + 8192;
    const int r  = t >> 1;               // 0..127 local row
    const int d0 = (t & 1) * 32;

    const float l = lpart[u0*128 + r] + lpart[(u0 + 1)*128 + r];
    const float inv = 1.0f / l;
    const size_t grow = (size_t)((16 + qtp)*128 + r) * DMODEL + h*64 + d0;
    #pragma unroll
    for (int i = 0; i < 4; ++i) {        // 4 groups of 8
        bf16x8 pk;
        #pragma unroll
        for (int j = 0; j < 2; ++j) {
            const float4 p0 = *reinterpret_cast<const float4*>(&part[b0 + r*64 + d0 + i*8 + j*4]);
            const float4 p1 = *reinterpret_cast<const float4*>(&part[b1 + r*64 + d0 + i*8 + j*4]);
            pk[j*4+0] = (__bf16)((p0.x + p1.x) * inv);
            pk[j*4+1] = (__bf16)((p0.y + p1.y) * inv);
            pk[j*4+2] = (__bf16)((p0.z + p1.z) * inv);
            pk[j*4+3] = (__bf16)((p0.w + p1.w) * inv);
        }
        *reinterpret_cast<bf16x8*>(&O[grow + i*8]) = pk;
    }
}

// ---------------------------------------------------------------------------
extern "C" void kernel_launch(void* const* d_in, const int* in_sizes, int n_in,
                              void* d_out, int out_size, void* d_ws, size_t ws_size,
                              hipStream_t stream) {
    const float* x  = (const float*)d_in[0];
    const float* Wq = (const float*)d_in[1];
    const float* bq = (const float*)d_in[2];
    const float* Wk = (const float*)d_in[3];
    const float* bk = (const float*)d_in[4];
    const float* Wv = (const float*)d_in[5];
    const float* bv = (const float*)d_in[6];
    const float* Wo = (const float*)d_in[7];
    const float* bo = (const float*)d_in[8];
    float* out = (float*)d_out;

    const size_t M1 = 1u << 20;
    __bf16* base = (__bf16*)d_ws;
    __bf16*    xb   = base;                          // 4M bf16
    __bf16*    Wcat = base + 4*M1;                   // Wq|Wk|Wv (3M bf16)
    __bf16*    Wob  = base + 7*M1;                   // 1M bf16
    _Float16*  Qh   = (_Float16*)(base + 8*M1);      // 4M fp16 each
    _Float16*  Kh   = (_Float16*)(base + 12*M1);
    _Float16*  Vth  = (_Float16*)(base + 16*M1);
    __bf16*    Ob   = base + 20*M1;                  // 4M bf16
    float*     lpart = (float*)(base + 24*M1);       // 512*128 fp32 = 256 KB
    float*     part  = out;                          // fp32 partials: exact 16 MB fit

    cvt_all<<<4096, 256, 0, stream>>>(x, Wq, Wk, Wv, Wo, base);
    gemm_qkv<<<dim3(24, 32), 256, 0, stream>>>(xb, Wcat, bq, bk, bv, Qh, Kh, Vth);
    attn_mfma<<<dim3(48, NH), 256, 0, stream>>>(Qh, Kh, Vth, Ob, part, lpart);
    attn_combine<<<dim3(16, NH), 256, 0, stream>>>(part, lpart, Ob);
    gemm_out<<<dim3(16, 32), 256, 0, stream>>>(Ob, Wob, bo, out);
}